// Round 7
// baseline (295.855 us; speedup 1.0000x reference)
//
#include <hip/hip_runtime.h>

#define BN 16384   // B*N rows
#define NN 2048    // N
#define DD 64      // hidden
#define CC 16      // classes
#define KS1 8      // K-splits gemm1
#define KS2 16     // K-splits gemm2

typedef short bf16x8 __attribute__((ext_vector_type(8)));
typedef float f32x4 __attribute__((ext_vector_type(4)));
typedef unsigned short u16x4 __attribute__((ext_vector_type(4)));

__device__ __forceinline__ f32x4 mfma16(bf16x8 a, bf16x8 b, f32x4 c) {
  return __builtin_amdgcn_mfma_f32_16x16x32_bf16(a, b, c, 0, 0, 0);
}
__device__ __forceinline__ unsigned short f2bf(float f) {   // RNE
  unsigned u = __float_as_uint(f);
  return (unsigned short)((u + 0x7FFFu + ((u >> 16) & 1u)) >> 16);
}
__device__ __forceinline__ float bf2f(unsigned short h) {
  return __uint_as_float(((unsigned)h) << 16);
}

// ---------------- threefry-2x32 dropout mask (JAX key(42)) ----------------
__device__ __forceinline__ unsigned tf_bits(unsigned i) {
  unsigned x0 = 0u;
  unsigned x1 = i;
  const unsigned k0 = 0u, k1 = 42u, k2 = 0x1BD11BDAu ^ 0u ^ 42u;
  x0 += k0; x1 += k1;
#define TFR(r) { x0 += x1; x1 = (x1 << (r)) | (x1 >> (32 - (r))); x1 ^= x0; }
  TFR(13) TFR(15) TFR(26) TFR(6)
  x0 += k1; x1 += k2 + 1u;
  TFR(17) TFR(29) TFR(16) TFR(24)
  x0 += k2; x1 += k0 + 2u;
  TFR(13) TFR(15) TFR(26) TFR(6)
  x0 += k0; x1 += k1 + 3u;
  TFR(17) TFR(29) TFR(16) TFR(24)
  x0 += k1; x1 += k2 + 4u;
  TFR(13) TFR(15) TFR(26) TFR(6)
  x0 += k2; x1 += k0 + 5u;
#undef TFR
  return x0 ^ x1;
}

// ==================== bf16-MFMA + atomic-accumulate PATH ====================

// ---- k_zero: zero S1 (4MB) + S2 (1MB) contiguous = 1,310,720 floats ------
__global__ __launch_bounds__(256) void k_zero(float* __restrict__ S)
{
  const f32x4 z = 0.f;
  ((f32x4*)S)[blockIdx.x * 256 + threadIdx.x] = z;
}

// ---- k_deg: degrees + A->bf16 + Y1 = dis*(X@W1) (fused; one pass over A) -
__global__ __launch_bounds__(256) void k_deg(const float* __restrict__ A,
    const float* __restrict__ X, const float* __restrict__ W1,
    float* __restrict__ dis, unsigned short* __restrict__ Abf,
    unsigned short* __restrict__ Y1s, unsigned short* __restrict__ Y1sT)
{
  const int w = threadIdx.x >> 6, lane = threadIdx.x & 63;
  const size_t row = (size_t)blockIdx.x * 4 + w;
  const float4* Arow = (const float4*)(A + row * NN);
  unsigned short* Brow = Abf + row * NN;
  float s = 0.f;
#pragma unroll
  for (int it = 0; it < 8; ++it) {
    float4 v = Arow[lane + 64 * it];
    s += (v.x + v.y) + (v.z + v.w);
    u16x4 p = { f2bf(v.x), f2bf(v.y), f2bf(v.z), f2bf(v.w) };
    *(u16x4*)(Brow + lane * 4 + it * 256) = p;
  }
#pragma unroll
  for (int m = 32; m; m >>= 1) s += __shfl_xor(s, m, 64);
  const float dv = 1.0f / sqrtf(s + 1.0f);   // A_tilda = A + I
  if (lane == 0) dis[row] = dv;
  // Y1 row (fp32 accumulate): X row is wave-uniform -> scalar loads
  const float* Xr = X + row * DD;
  float acc = 0.f;
#pragma unroll
  for (int k = 0; k < DD; ++k) acc += Xr[k] * W1[k * DD + lane];
  const unsigned short yv = f2bf(dv * acc);
  Y1s[row * DD + lane] = yv;
  const int b = (int)(row >> 11), kr = (int)(row & (NN - 1));
  Y1sT[((size_t)b * DD + lane) * NN + kr] = yv;     // transposed (B-operand)
}

// ---- k_gemm1: S1 += Abf @ Y1 (bf16 MFMA, atomic over KS1=8) --------------
// 4M x 2N per wave; grid = 64 Mb x 2 Nhalf x 8 KS = 1024.
__global__ __launch_bounds__(256, 4) void k_gemm1(const unsigned short* __restrict__ Abf,
    const unsigned short* __restrict__ Y1sT, float* __restrict__ S1)
{
  const int Mb = blockIdx.x >> 4;                 // 0..63 (256-row tiles)
  const int ns = (blockIdx.x >> 3) & 1;           // N half (32 cols)
  const int ks = blockIdx.x & 7;                  // K split (256 K)
  const int w = __builtin_amdgcn_readfirstlane((int)threadIdx.x >> 6);
  const int lane = threadIdx.x & 63;
  const int m15 = lane & 15, quad = lane >> 4;
  const int b = Mb >> 3;                          // 8 blocks per batch
  const int k0 = ks * 256 + quad * 8;
  const unsigned short* Ap[4];
#pragma unroll
  for (int m = 0; m < 4; ++m)
    Ap[m] = Abf + ((size_t)Mb * 256 + m * 64 + w * 16 + m15) * NN + k0;
  const unsigned short* Bp0 = Y1sT + ((size_t)b * DD + ns * 32 + m15) * NN + k0;
  const unsigned short* Bp1 = Bp0 + (size_t)16 * NN;
  const f32x4 zero = 0.f;
  f32x4 acc[4][2];
#pragma unroll
  for (int m = 0; m < 4; ++m) { acc[m][0] = zero; acc[m][1] = zero; }
  bf16x8 a[4], b0, b1;
#pragma unroll
  for (int m = 0; m < 4; ++m) a[m] = *(const bf16x8*)Ap[m];
  b0 = *(const bf16x8*)Bp0;
  b1 = *(const bf16x8*)Bp1;
#pragma unroll 1
  for (int kk = 0; kk < 8; ++kk) {
    const int off = (kk < 7) ? (kk + 1) * 32 : 0;  // wrap: harmless re-read
    bf16x8 na[4], nb0, nb1;
#pragma unroll
    for (int m = 0; m < 4; ++m) na[m] = *(const bf16x8*)(Ap[m] + off);
    nb0 = *(const bf16x8*)(Bp0 + off);
    nb1 = *(const bf16x8*)(Bp1 + off);
#pragma unroll
    for (int m = 0; m < 4; ++m) {
      acc[m][0] = mfma16(a[m], b0, acc[m][0]);
      acc[m][1] = mfma16(a[m], b1, acc[m][1]);
    }
#pragma unroll
    for (int m = 0; m < 4; ++m) a[m] = na[m];
    b0 = nb0; b1 = nb1;
  }
#pragma unroll
  for (int m = 0; m < 4; ++m)
#pragma unroll
    for (int t = 0; t < 2; ++t)
#pragma unroll
      for (int r = 0; r < 4; ++r)
        atomicAdd(&S1[((size_t)Mb * 256 + m * 64 + w * 16 + quad * 4 + r) * DD
                      + ns * 32 + t * 16 + m15], acc[m][t][r]);
}

// ---- k_epi1: h = dropout(relu(dis*S1+diag+b1)); Y2 = dis*(h@W2) ----------
// writes Y2sT (bf16, B-operand) and S2 diag term (fp32, plain store).
// 16 rows/block, grid 1024.
__global__ __launch_bounds__(256) void k_epi1(const float* __restrict__ S1,
    const unsigned short* __restrict__ Y1s, const float* __restrict__ dis,
    const float* __restrict__ b1, const float* __restrict__ W2,
    unsigned short* __restrict__ Y2sT, float* __restrict__ S2)
{
  __shared__ float hs[16][65];
  __shared__ float W2l[DD * CC];
  const int tid = threadIdx.x;
  *(float4*)(W2l + tid * 4) = *(const float4*)(W2 + tid * 4);   // 1024 floats
  const int r0 = blockIdx.x * 16;
#pragma unroll
  for (int j = 0; j < 4; ++j) {
    const int e = tid + j * 256;                   // 0..1023 = 16 rows x 64
    const int rl = e >> 6, n = e & 63;
    const size_t row = (size_t)r0 + rl;
    const size_t o = row * DD + n;
    const float z = bf2f(Y1s[o]) + S1[o];          // diag + A-sum (complete)
    float h = fmaxf(dis[row] * z + b1[n], 0.f);
    const unsigned bits = tf_bits((unsigned)o);
    hs[rl][n] = (bits >> 31) ? 0.f : (h + h);      // p=0.5, scale 2
  }
  __syncthreads();
  const int c = tid & 15, rl = tid >> 4;           // 256 = 16 rows x 16 cols
  float s = 0.f;
#pragma unroll
  for (int k = 0; k < DD; ++k) s += hs[rl][k] * W2l[k * CC + c];
  const int row = r0 + rl;
  const int b = row >> 11, kr = row & (NN - 1);
  const float y2 = dis[row] * s;
  Y2sT[((size_t)b * CC + c) * NN + kr] = f2bf(y2);
  S2[(size_t)row * CC + c] = y2;                   // layer-2 diag term (fp32)
}

// ---- k_gemm2: S2 += Abf @ Y2 (bf16 MFMA, atomic over KS2=16) -------------
// 4M x 1N per wave; grid = 64 Mb x 16 KS = 1024.
__global__ __launch_bounds__(256, 4) void k_gemm2(const unsigned short* __restrict__ Abf,
    const unsigned short* __restrict__ Y2sT, float* __restrict__ S2)
{
  const int Mb = blockIdx.x >> 4;                 // 0..63
  const int ks = blockIdx.x & 15;                 // K split (128 K)
  const int w = __builtin_amdgcn_readfirstlane((int)threadIdx.x >> 6);
  const int lane = threadIdx.x & 63;
  const int m15 = lane & 15, quad = lane >> 4;
  const int b = Mb >> 3;
  const int k0 = ks * 128 + quad * 8;
  const unsigned short* Ap[4];
#pragma unroll
  for (int m = 0; m < 4; ++m)
    Ap[m] = Abf + ((size_t)Mb * 256 + m * 64 + w * 16 + m15) * NN + k0;
  const unsigned short* Bp = Y2sT + ((size_t)b * CC + m15) * NN + k0;
  const f32x4 zero = 0.f;
  f32x4 acc[4];
#pragma unroll
  for (int m = 0; m < 4; ++m) acc[m] = zero;
  bf16x8 a[4], bb;
#pragma unroll
  for (int m = 0; m < 4; ++m) a[m] = *(const bf16x8*)Ap[m];
  bb = *(const bf16x8*)Bp;
#pragma unroll 1
  for (int kk = 0; kk < 4; ++kk) {
    const int off = (kk < 3) ? (kk + 1) * 32 : 0;
    bf16x8 na[4], nbb;
#pragma unroll
    for (int m = 0; m < 4; ++m) na[m] = *(const bf16x8*)(Ap[m] + off);
    nbb = *(const bf16x8*)(Bp + off);
#pragma unroll
    for (int m = 0; m < 4; ++m) acc[m] = mfma16(a[m], bb, acc[m]);
#pragma unroll
    for (int m = 0; m < 4; ++m) a[m] = na[m];
    bb = nbb;
  }
#pragma unroll
  for (int m = 0; m < 4; ++m)
#pragma unroll
    for (int r = 0; r < 4; ++r)
      atomicAdd(&S2[((size_t)Mb * 256 + m * 64 + w * 16 + quad * 4 + r) * CC + m15],
                acc[m][r]);
}

// ---- k_final: out = dis*S2 + b2 (1 MB read, 1 MB write) ------------------
__global__ __launch_bounds__(256) void k_final(const float* __restrict__ S2,
    const float* __restrict__ dis, const float* __restrict__ b2,
    float* __restrict__ out)
{
  const int gid = blockIdx.x * 256 + threadIdx.x;   // 65536 float4 groups
  const int r = gid >> 2, q = gid & 3;
  const size_t o = (size_t)r * CC + q * 4;
  const float4 s = *(const float4*)(S2 + o);
  const float dv = dis[r];
  const float4 bb = *(const float4*)(b2 + q * 4);
  float4 res;
  res.x = dv * s.x + bb.x;
  res.y = dv * s.y + bb.y;
  res.z = dv * s.z + bb.z;
  res.w = dv * s.w + bb.w;
  *(float4*)(out + o) = res;
}

// ==================== FALLBACK fp32 PATH (R3, proven) ====================
#define FKS1 4
#define FKS2 16

__global__ __launch_bounds__(256) void d_deg_xw(const float* __restrict__ A,
    const float* __restrict__ X, const float* __restrict__ W1,
    float* __restrict__ dis, float* __restrict__ Y1s)
{
  const int w = threadIdx.x >> 6, lane = threadIdx.x & 63;
  const int row = __builtin_amdgcn_readfirstlane(blockIdx.x * 4 + w);
  const float4* Arow = (const float4*)(A + (size_t)row * NN);
  float s = 0.f;
#pragma unroll
  for (int it = 0; it < 8; ++it) {
    float4 v = Arow[lane + 64 * it];
    s += v.x + v.y + v.z + v.w;
  }
#pragma unroll
  for (int m = 32; m; m >>= 1) s += __shfl_xor(s, m, 64);
  const float dv = 1.0f / sqrtf(s + 1.0f);
  if (lane == 0) dis[row] = dv;
  const float* Xr = X + (size_t)row * DD;
  float acc = 0.f;
#pragma unroll
  for (int k = 0; k < DD; ++k) acc += Xr[k] * W1[k * DD + lane];
  Y1s[(size_t)row * DD + lane] = dv * acc;
}

__global__ __launch_bounds__(256) void d_gemm1(const float* __restrict__ A,
    const float* __restrict__ Y1s, float* __restrict__ Z1)
{
  const int rb = blockIdx.x >> 2, ks = blockIdx.x & (FKS1 - 1);
  const int lane = threadIdx.x & 63;
  const int c0 = __builtin_amdgcn_readfirstlane((threadIdx.x >> 6) << 4);
  const int row = rb * 64 + lane;
  const int batch = rb >> 5;
  const int KSEG = NN / FKS1;
  const float* Arow = A + (size_t)row * NN + ks * KSEG;
  const float* Yb = Y1s + (size_t)batch * NN * DD + c0;
  const int kbase = ks * KSEG;
  float acc[16];
#pragma unroll
  for (int c = 0; c < 16; ++c) acc[c] = 0.f;
  float4 a0 = *(const float4*)(Arow);
  float4 a1 = *(const float4*)(Arow + 4);
  float4 a2 = *(const float4*)(Arow + 8);
  float4 a3 = *(const float4*)(Arow + 12);
  for (int k = 0; k < KSEG; k += 16) {
    const int kn = (k + 16 < KSEG) ? (k + 16) : 0;
    float4 n0 = *(const float4*)(Arow + kn);
    float4 n1 = *(const float4*)(Arow + kn + 4);
    float4 n2 = *(const float4*)(Arow + kn + 8);
    float4 n3 = *(const float4*)(Arow + kn + 12);
    const float* y0 = Yb + (size_t)(kbase + k) * DD;
    const float av[16] = {a0.x, a0.y, a0.z, a0.w, a1.x, a1.y, a1.z, a1.w,
                          a2.x, a2.y, a2.z, a2.w, a3.x, a3.y, a3.z, a3.w};
#pragma unroll
    for (int j = 0; j < 16; ++j) {
      const float* yr = y0 + j * DD;
#pragma unroll
      for (int c = 0; c < 16; ++c) acc[c] += av[j] * yr[c];
    }
    a0 = n0; a1 = n1; a2 = n2; a3 = n3;
  }
  float* Zp = Z1 + ((size_t)ks * BN + row) * DD + c0;
#pragma unroll
  for (int c = 0; c < 16; c += 4) {
    float4 v; v.x = acc[c]; v.y = acc[c+1]; v.z = acc[c+2]; v.w = acc[c+3];
    *(float4*)(Zp + c) = v;
  }
}

__global__ __launch_bounds__(256) void d_epi1(const float* __restrict__ Z1,
    const float* __restrict__ Y1s, const float* __restrict__ dis,
    const float* __restrict__ b1, const float* __restrict__ W2,
    float* __restrict__ Y2s)
{
  __shared__ float W2l[DD * CC];
  __shared__ float hl[4][DD];
  const int tid = threadIdx.x;
  *(float4*)(W2l + tid * 4) = *(const float4*)(W2 + tid * 4);
  const int w = tid >> 6, lane = tid & 63;
  const int row = blockIdx.x * 4 + w;
  const size_t o = (size_t)row * DD + lane;
  float z = Y1s[o];
#pragma unroll
  for (int p = 0; p < FKS1; ++p) z += Z1[(size_t)p * BN * DD + o];
  const float dv = dis[row];
  float h = fmaxf(dv * z + b1[lane], 0.f);
  const unsigned bits = tf_bits((unsigned)o);
  h = (bits >> 31) ? 0.f : (h + h);
  hl[w][lane] = h;
  __syncthreads();
  const int wr = tid >> 6, l = tid & 63;
  const int c = l & 15, kq = l >> 4;
  float p = 0.f;
#pragma unroll
  for (int kk = 0; kk < 16; ++kk)
    p += hl[wr][kq * 16 + kk] * W2l[(kq * 16 + kk) * CC + c];
  p += __shfl_xor(p, 16, 64);
  p += __shfl_xor(p, 32, 64);
  if (l < 16) {
    const int rg = blockIdx.x * 4 + wr;
    Y2s[(size_t)rg * CC + c] = dis[rg] * p;
  }
}

__global__ __launch_bounds__(256) void d_gemm2(const float* __restrict__ A,
    const float* __restrict__ Y2s, float* __restrict__ Z2)
{
  const int rb = blockIdx.x >> 4, ks = blockIdx.x & (FKS2 - 1);
  const int row = rb * 256 + threadIdx.x;
  const int batch = rb >> 3;
  const int KSEG = NN / FKS2;
  const float* Arow = A + (size_t)row * NN + ks * KSEG;
  const float* Yb = Y2s + (size_t)batch * NN * CC;
  const int kbase = ks * KSEG;
  float acc[16];
#pragma unroll
  for (int c = 0; c < 16; ++c) acc[c] = 0.f;
  float4 a0 = *(const float4*)(Arow);
  float4 a1 = *(const float4*)(Arow + 4);
  for (int k = 0; k < KSEG; k += 8) {
    const int kn = (k + 8 < KSEG) ? (k + 8) : 0;
    float4 n0 = *(const float4*)(Arow + kn);
    float4 n1 = *(const float4*)(Arow + kn + 4);
    const float av[8] = {a0.x, a0.y, a0.z, a0.w, a1.x, a1.y, a1.z, a1.w};
#pragma unroll
    for (int j = 0; j < 8; ++j) {
      const float* yr = Yb + (size_t)(kbase + k + j) * CC;
#pragma unroll
      for (int c = 0; c < 16; ++c) acc[c] += av[j] * yr[c];
    }
    a0 = n0; a1 = n1;
  }
  float* Zp = Z2 + ((size_t)ks * BN + row) * CC;
#pragma unroll
  for (int c = 0; c < 16; c += 4) {
    float4 v; v.x = acc[c]; v.y = acc[c+1]; v.z = acc[c+2]; v.w = acc[c+3];
    *(float4*)(Zp + c) = v;
  }
}

__global__ __launch_bounds__(256) void d_final(const float* __restrict__ Z2,
    const float* __restrict__ Y2s, const float* __restrict__ dis,
    const float* __restrict__ b2, float* __restrict__ out)
{
  const int gid = blockIdx.x * 256 + threadIdx.x;
  const int r = gid >> 2, q = gid & 3;
  const size_t o = (size_t)r * CC + q * 4;
  float4 s = *(const float4*)(Y2s + o);
#pragma unroll
  for (int p = 0; p < FKS2; ++p) {
    const float4 zp = *(const float4*)(Z2 + (size_t)p * BN * CC + o);
    s.x += zp.x; s.y += zp.y; s.z += zp.z; s.w += zp.w;
  }
  const float dv = dis[r];
  const float4 bb = *(const float4*)(b2 + q * 4);
  float4 res;
  res.x = dv * s.x + bb.x;
  res.y = dv * s.y + bb.y;
  res.z = dv * s.z + bb.z;
  res.w = dv * s.w + bb.w;
  *(float4*)(out + o) = res;
}

extern "C" void kernel_launch(void* const* d_in, const int* in_sizes, int n_in,
                              void* d_out, int out_size, void* d_ws, size_t ws_size,
                              hipStream_t stream) {
  const float* X  = (const float*)d_in[0];
  const float* A  = (const float*)d_in[1];
  const float* W1 = (const float*)d_in[2];
  const float* b1 = (const float*)d_in[3];
  const float* W2 = (const float*)d_in[4];
  const float* b2 = (const float*)d_in[5];
  float* out = (float*)d_out;
  char* wsb = (char*)d_ws;

  // ws layout (bytes): Abf 64MB @0 | S1 4MB @64M | S2 1MB (contig w/ S1) |
  // dis 64KB | Y1s 2MB | Y1sT 2MB | Y2sT 0.5MB  => 77,135,872 total
  const size_t NEED = 77135872;
  if (ws_size >= NEED) {
    unsigned short* Abf  = (unsigned short*)wsb;
    float*          S1   = (float*)(wsb + 67108864);   // 4 MB
    float*          S2   = (float*)(wsb + 71303168);   // 1 MB (contig after S1)
    float*          dis  = (float*)(wsb + 72351744);
    unsigned short* Y1s  = (unsigned short*)(wsb + 72417280);
    unsigned short* Y1sT = (unsigned short*)(wsb + 74514432);
    unsigned short* Y2sT = (unsigned short*)(wsb + 76611584);

    k_zero <<<1280,    256, 0, stream>>>(S1);          // S1+S2 = 5 MB contig
    k_deg  <<<BN / 4,  256, 0, stream>>>(A, X, W1, dis, Abf, Y1s, Y1sT);
    k_gemm1<<<1024,    256, 0, stream>>>(Abf, Y1sT, S1);
    k_epi1 <<<BN / 16, 256, 0, stream>>>(S1, Y1s, dis, b1, W2, Y2sT, S2);
    k_gemm2<<<1024,    256, 0, stream>>>(Abf, Y2sT, S2);
    k_final<<<256,     256, 0, stream>>>(S2, dis, b2, out);
  } else {
    // fallback: proven fp32 path (R3)
    float* ws  = (float*)d_ws;
    float* dis = ws;
    float* Y1s = ws + 16384;
    float* Z1  = Y1s + (size_t)BN * DD;
    float* Z2  = Z1;
    float* Y2s = Z1 + (size_t)FKS1 * BN * DD;

    d_deg_xw<<<BN / 4,     256, 0, stream>>>(A, X, W1, dis, Y1s);
    d_gemm1 <<<256 * FKS1, 256, 0, stream>>>(A, Y1s, Z1);
    d_epi1  <<<BN / 4,     256, 0, stream>>>(Z1, Y1s, dis, b1, W2, Y2s);
    d_gemm2 <<<64 * FKS2,  256, 0, stream>>>(A, Y2s, Z2);
    d_final <<<256,        256, 0, stream>>>(Z2, Y2s, dis, b2, out);
  }
}

// Round 8
// 270.613 us; speedup vs baseline: 1.0933x; 1.0933x over previous
//
#include <hip/hip_runtime.h>

#define BN 16384   // B*N rows
#define NN 2048    // N
#define DD 64      // hidden
#define CC 16      // classes

typedef short bf16x8 __attribute__((ext_vector_type(8)));
typedef float f32x4 __attribute__((ext_vector_type(4)));
typedef unsigned short u16x4 __attribute__((ext_vector_type(4)));

__device__ __forceinline__ f32x4 mfma16(bf16x8 a, bf16x8 b, f32x4 c) {
  return __builtin_amdgcn_mfma_f32_16x16x32_bf16(a, b, c, 0, 0, 0);
}
__device__ __forceinline__ unsigned short f2bf(float f) {   // RNE
  unsigned u = __float_as_uint(f);
  return (unsigned short)((u + 0x7FFFu + ((u >> 16) & 1u)) >> 16);
}
__device__ __forceinline__ float bf2f(unsigned short h) {
  return __uint_as_float(((unsigned)h) << 16);
}

// ---------------- threefry-2x32 dropout mask (JAX key(42)) ----------------
__device__ __forceinline__ unsigned tf_bits(unsigned i) {
  unsigned x0 = 0u;
  unsigned x1 = i;
  const unsigned k0 = 0u, k1 = 42u, k2 = 0x1BD11BDAu ^ 0u ^ 42u;
  x0 += k0; x1 += k1;
#define TFR(r) { x0 += x1; x1 = (x1 << (r)) | (x1 >> (32 - (r))); x1 ^= x0; }
  TFR(13) TFR(15) TFR(26) TFR(6)
  x0 += k1; x1 += k2 + 1u;
  TFR(17) TFR(29) TFR(16) TFR(24)
  x0 += k2; x1 += k0 + 2u;
  TFR(13) TFR(15) TFR(26) TFR(6)
  x0 += k0; x1 += k1 + 3u;
  TFR(17) TFR(29) TFR(16) TFR(24)
  x0 += k1; x1 += k2 + 4u;
  TFR(13) TFR(15) TFR(26) TFR(6)
  x0 += k2; x1 += k0 + 5u;
#undef TFR
  return x0 ^ x1;
}

// ==================== bf16-MFMA + in-block K-split PATH ====================

// ---- k_deg: degrees + A->bf16 + Y1 = dis*(X@W1) (fused; one pass over A) -
__global__ __launch_bounds__(256) void k_deg(const float* __restrict__ A,
    const float* __restrict__ X, const float* __restrict__ W1,
    float* __restrict__ dis, unsigned short* __restrict__ Abf,
    unsigned short* __restrict__ Y1s, unsigned short* __restrict__ Y1sT)
{
  const int w = threadIdx.x >> 6, lane = threadIdx.x & 63;
  const size_t row = (size_t)blockIdx.x * 4 + w;
  const float4* Arow = (const float4*)(A + row * NN);
  unsigned short* Brow = Abf + row * NN;
  float s = 0.f;
#pragma unroll
  for (int it = 0; it < 8; ++it) {
    float4 v = Arow[lane + 64 * it];
    s += (v.x + v.y) + (v.z + v.w);
    u16x4 p = { f2bf(v.x), f2bf(v.y), f2bf(v.z), f2bf(v.w) };
    *(u16x4*)(Brow + lane * 4 + it * 256) = p;
  }
#pragma unroll
  for (int m = 32; m; m >>= 1) s += __shfl_xor(s, m, 64);
  const float dv = 1.0f / sqrtf(s + 1.0f);   // A_tilda = A + I
  if (lane == 0) dis[row] = dv;
  // Y1 row (fp32 accumulate): X row is wave-uniform -> scalar loads
  const float* Xr = X + row * DD;
  float acc = 0.f;
#pragma unroll
  for (int k = 0; k < DD; ++k) acc += Xr[k] * W1[k * DD + lane];
  const unsigned short yv = f2bf(dv * acc);
  Y1s[row * DD + lane] = yv;
  const int b = (int)(row >> 11), kr = (int)(row & (NN - 1));
  Y1sT[((size_t)b * DD + lane) * NN + kr] = yv;     // transposed (B-operand)
}

// ---- k_gemm1h: h-tile = dropout(relu(dis*(A@Y1 + diag) + b1)) ------------
// 32 rows x 32 cols per block; 4 waves K-split 4x512, LDS reduce; full
// layer-1 epilogue fused; writes h bf16 row-major. grid = 512 Mb x 2 ns.
__global__ __launch_bounds__(256, 4) void k_gemm1h(const unsigned short* __restrict__ Abf,
    const unsigned short* __restrict__ Y1sT, const unsigned short* __restrict__ Y1s,
    const float* __restrict__ dis, const float* __restrict__ b1,
    unsigned short* __restrict__ Hbf)
{
  __shared__ float red[4][32][36];
  const int Mb = blockIdx.x >> 1;                 // 0..511 (32-row tiles)
  const int ns = blockIdx.x & 1;                  // N half (32 cols)
  const int w = __builtin_amdgcn_readfirstlane((int)threadIdx.x >> 6);
  const int lane = threadIdx.x & 63;
  const int m15 = lane & 15, quad = lane >> 4;
  const int b = Mb >> 6;                          // 64 Mb per batch
  const int k0 = w * 512 + quad * 8;              // wave K-split
  const unsigned short* Ap0 = Abf + ((size_t)Mb * 32 + m15) * NN + k0;
  const unsigned short* Ap1 = Ap0 + (size_t)16 * NN;
  const unsigned short* Bp0 = Y1sT + ((size_t)b * DD + ns * 32 + m15) * NN + k0;
  const unsigned short* Bp1 = Bp0 + (size_t)16 * NN;
  const f32x4 zero = 0.f;
  f32x4 acc[2][2];
  acc[0][0] = zero; acc[0][1] = zero; acc[1][0] = zero; acc[1][1] = zero;
  bf16x8 a0 = *(const bf16x8*)Ap0, a1 = *(const bf16x8*)Ap1;
  bf16x8 b0 = *(const bf16x8*)Bp0, b1v = *(const bf16x8*)Bp1;
#pragma unroll 1
  for (int kk = 0; kk < 16; ++kk) {
    const int off = (kk < 15) ? (kk + 1) * 32 : 0;  // wrap: harmless re-read
    bf16x8 na0 = *(const bf16x8*)(Ap0 + off);
    bf16x8 na1 = *(const bf16x8*)(Ap1 + off);
    bf16x8 nb0 = *(const bf16x8*)(Bp0 + off);
    bf16x8 nb1 = *(const bf16x8*)(Bp1 + off);
    acc[0][0] = mfma16(a0, b0, acc[0][0]);
    acc[0][1] = mfma16(a0, b1v, acc[0][1]);
    acc[1][0] = mfma16(a1, b0, acc[1][0]);
    acc[1][1] = mfma16(a1, b1v, acc[1][1]);
    a0 = na0; a1 = na1; b0 = nb0; b1v = nb1;
  }
  // write wave partials to LDS (C layout: row=quad*4+r, col=m15)
#pragma unroll
  for (int mi = 0; mi < 2; ++mi)
#pragma unroll
    for (int ni = 0; ni < 2; ++ni)
#pragma unroll
      for (int r = 0; r < 4; ++r)
        red[w][mi * 16 + quad * 4 + r][ni * 16 + m15] = acc[mi][ni][r];
  __syncthreads();
  // reduce 4 wave-partials + layer-1 epilogue; thread: 1 row x 4 cols
  const int tid = threadIdx.x;
  const int rowl = tid >> 3, c0 = (tid & 7) * 4;
  f32x4 sum = *(const f32x4*)&red[0][rowl][c0];
  sum += *(const f32x4*)&red[1][rowl][c0];
  sum += *(const f32x4*)&red[2][rowl][c0];
  sum += *(const f32x4*)&red[3][rowl][c0];
  const int grow = Mb * 32 + rowl;
  const int gcol0 = ns * 32 + c0;
  const u16x4 y1d = *(const u16x4*)(Y1s + (size_t)grow * DD + gcol0);
  const float4 b1q = *(const float4*)(b1 + gcol0);
  const float dv = dis[grow];
  const unsigned o0 = (unsigned)grow * DD + gcol0;
  u16x4 hq;
#pragma unroll
  for (int j = 0; j < 4; ++j) {
    const float z = sum[j] + bf2f(y1d[j]);
    const float bj = j == 0 ? b1q.x : j == 1 ? b1q.y : j == 2 ? b1q.z : b1q.w;
    float h = fmaxf(dv * z + bj, 0.f);
    const unsigned bits = tf_bits(o0 + j);
    hq[j] = (bits >> 31) ? (unsigned short)0 : f2bf(h + h);  // p=0.5, x2
  }
  *(u16x4*)(Hbf + (size_t)grow * DD + gcol0) = hq;
}

// ---- k_epi1: Y2 = dis*(h@W2) -> Y2sT bf16 + S2d fp32 (diag term) ---------
// 16 rows/block, grid 1024; reads only the 2 MB h.
__global__ __launch_bounds__(256) void k_epi1(const unsigned short* __restrict__ Hbf,
    const float* __restrict__ dis, const float* __restrict__ W2,
    unsigned short* __restrict__ Y2sT, float* __restrict__ S2d)
{
  __shared__ float hs[16][68];
  __shared__ float W2l[DD * CC];
  const int tid = threadIdx.x;
  *(float4*)(W2l + tid * 4) = *(const float4*)(W2 + tid * 4);   // 1024 floats
  const int r0 = blockIdx.x * 16;
  {
    const int rl = tid >> 4, cl = (tid & 15) * 4;                // 16x64 tile
    const u16x4 hv = *(const u16x4*)(Hbf + ((size_t)r0 + rl) * DD + cl);
    hs[rl][cl + 0] = bf2f(hv[0]);
    hs[rl][cl + 1] = bf2f(hv[1]);
    hs[rl][cl + 2] = bf2f(hv[2]);
    hs[rl][cl + 3] = bf2f(hv[3]);
  }
  __syncthreads();
  const int c = tid & 15, rl = tid >> 4;           // 256 = 16 rows x 16 cols
  float s = 0.f;
#pragma unroll
  for (int k = 0; k < DD; ++k) s += hs[rl][k] * W2l[k * CC + c];
  const int row = r0 + rl;
  const int b = row >> 11, kr = row & (NN - 1);
  const float y2 = dis[row] * s;
  Y2sT[((size_t)b * CC + c) * NN + kr] = f2bf(y2);
  S2d[(size_t)row * CC + c] = y2;                  // layer-2 diag (fp32)
}

// ---- k_gemm2o: out = dis*(A@Y2 + diag) + b2 (fused final) ----------------
// 16 rows x 16 cols per block; 4 waves K-split 4x512, LDS reduce. grid 1024.
__global__ __launch_bounds__(256, 4) void k_gemm2o(const unsigned short* __restrict__ Abf,
    const unsigned short* __restrict__ Y2sT, const float* __restrict__ S2d,
    const float* __restrict__ dis, const float* __restrict__ b2,
    float* __restrict__ out)
{
  __shared__ float red[4][16][20];
  const int Mb = blockIdx.x;                      // 0..1023 (16-row tiles)
  const int w = __builtin_amdgcn_readfirstlane((int)threadIdx.x >> 6);
  const int lane = threadIdx.x & 63;
  const int m15 = lane & 15, quad = lane >> 4;
  const int b = Mb >> 7;                          // 128 Mb per batch
  const int k0 = w * 512 + quad * 8;
  const unsigned short* Ap = Abf + ((size_t)Mb * 16 + m15) * NN + k0;
  const unsigned short* Bp = Y2sT + ((size_t)b * CC + m15) * NN + k0;
  const f32x4 zero = 0.f;
  f32x4 acc = zero;
  bf16x8 a = *(const bf16x8*)Ap;
  bf16x8 bb = *(const bf16x8*)Bp;
#pragma unroll 1
  for (int kk = 0; kk < 16; ++kk) {
    const int off = (kk < 15) ? (kk + 1) * 32 : 0;
    bf16x8 na = *(const bf16x8*)(Ap + off);
    bf16x8 nbb = *(const bf16x8*)(Bp + off);
    acc = mfma16(a, bb, acc);
    a = na; bb = nbb;
  }
#pragma unroll
  for (int r = 0; r < 4; ++r)
    red[w][quad * 4 + r][m15] = acc[r];
  __syncthreads();
  const int tid = threadIdx.x;
  const int rowl = tid >> 4, c = tid & 15;         // 256 = 16x16
  const float sum = red[0][rowl][c] + red[1][rowl][c]
                  + red[2][rowl][c] + red[3][rowl][c];
  const int grow = Mb * 16 + rowl;
  out[(size_t)grow * CC + c] =
      dis[grow] * (sum + S2d[(size_t)grow * CC + c]) + b2[c];
}

// ==================== FALLBACK fp32 PATH (R3, proven) ====================
#define FKS1 4
#define FKS2 16

__global__ __launch_bounds__(256) void d_deg_xw(const float* __restrict__ A,
    const float* __restrict__ X, const float* __restrict__ W1,
    float* __restrict__ dis, float* __restrict__ Y1s)
{
  const int w = threadIdx.x >> 6, lane = threadIdx.x & 63;
  const int row = __builtin_amdgcn_readfirstlane(blockIdx.x * 4 + w);
  const float4* Arow = (const float4*)(A + (size_t)row * NN);
  float s = 0.f;
#pragma unroll
  for (int it = 0; it < 8; ++it) {
    float4 v = Arow[lane + 64 * it];
    s += v.x + v.y + v.z + v.w;
  }
#pragma unroll
  for (int m = 32; m; m >>= 1) s += __shfl_xor(s, m, 64);
  const float dv = 1.0f / sqrtf(s + 1.0f);
  if (lane == 0) dis[row] = dv;
  const float* Xr = X + (size_t)row * DD;
  float acc = 0.f;
#pragma unroll
  for (int k = 0; k < DD; ++k) acc += Xr[k] * W1[k * DD + lane];
  Y1s[(size_t)row * DD + lane] = dv * acc;
}

__global__ __launch_bounds__(256) void d_gemm1(const float* __restrict__ A,
    const float* __restrict__ Y1s, float* __restrict__ Z1)
{
  const int rb = blockIdx.x >> 2, ks = blockIdx.x & (FKS1 - 1);
  const int lane = threadIdx.x & 63;
  const int c0 = __builtin_amdgcn_readfirstlane((threadIdx.x >> 6) << 4);
  const int row = rb * 64 + lane;
  const int batch = rb >> 5;
  const int KSEG = NN / FKS1;
  const float* Arow = A + (size_t)row * NN + ks * KSEG;
  const float* Yb = Y1s + (size_t)batch * NN * DD + c0;
  const int kbase = ks * KSEG;
  float acc[16];
#pragma unroll
  for (int c = 0; c < 16; ++c) acc[c] = 0.f;
  float4 a0 = *(const float4*)(Arow);
  float4 a1 = *(const float4*)(Arow + 4);
  float4 a2 = *(const float4*)(Arow + 8);
  float4 a3 = *(const float4*)(Arow + 12);
  for (int k = 0; k < KSEG; k += 16) {
    const int kn = (k + 16 < KSEG) ? (k + 16) : 0;
    float4 n0 = *(const float4*)(Arow + kn);
    float4 n1 = *(const float4*)(Arow + kn + 4);
    float4 n2 = *(const float4*)(Arow + kn + 8);
    float4 n3 = *(const float4*)(Arow + kn + 12);
    const float* y0 = Yb + (size_t)(kbase + k) * DD;
    const float av[16] = {a0.x, a0.y, a0.z, a0.w, a1.x, a1.y, a1.z, a1.w,
                          a2.x, a2.y, a2.z, a2.w, a3.x, a3.y, a3.z, a3.w};
#pragma unroll
    for (int j = 0; j < 16; ++j) {
      const float* yr = y0 + j * DD;
#pragma unroll
      for (int c = 0; c < 16; ++c) acc[c] += av[j] * yr[c];
    }
    a0 = n0; a1 = n1; a2 = n2; a3 = n3;
  }
  float* Zp = Z1 + ((size_t)ks * BN + row) * DD + c0;
#pragma unroll
  for (int c = 0; c < 16; c += 4) {
    float4 v; v.x = acc[c]; v.y = acc[c+1]; v.z = acc[c+2]; v.w = acc[c+3];
    *(float4*)(Zp + c) = v;
  }
}

__global__ __launch_bounds__(256) void d_epi1(const float* __restrict__ Z1,
    const float* __restrict__ Y1s, const float* __restrict__ dis,
    const float* __restrict__ b1, const float* __restrict__ W2,
    float* __restrict__ Y2s)
{
  __shared__ float W2l[DD * CC];
  __shared__ float hl[4][DD];
  const int tid = threadIdx.x;
  *(float4*)(W2l + tid * 4) = *(const float4*)(W2 + tid * 4);
  const int w = tid >> 6, lane = tid & 63;
  const int row = blockIdx.x * 4 + w;
  const size_t o = (size_t)row * DD + lane;
  float z = Y1s[o];
#pragma unroll
  for (int p = 0; p < FKS1; ++p) z += Z1[(size_t)p * BN * DD + o];
  const float dv = dis[row];
  float h = fmaxf(dv * z + b1[lane], 0.f);
  const unsigned bits = tf_bits((unsigned)o);
  h = (bits >> 31) ? 0.f : (h + h);
  hl[w][lane] = h;
  __syncthreads();
  const int wr = tid >> 6, l = tid & 63;
  const int c = l & 15, kq = l >> 4;
  float p = 0.f;
#pragma unroll
  for (int kk = 0; kk < 16; ++kk)
    p += hl[wr][kq * 16 + kk] * W2l[(kq * 16 + kk) * CC + c];
  p += __shfl_xor(p, 16, 64);
  p += __shfl_xor(p, 32, 64);
  if (l < 16) {
    const int rg = blockIdx.x * 4 + wr;
    Y2s[(size_t)rg * CC + c] = dis[rg] * p;
  }
}

__global__ __launch_bounds__(256) void d_gemm2(const float* __restrict__ A,
    const float* __restrict__ Y2s, float* __restrict__ Z2)
{
  const int rb = blockIdx.x >> 4, ks = blockIdx.x & (FKS2 - 1);
  const int row = rb * 256 + threadIdx.x;
  const int batch = rb >> 3;
  const int KSEG = NN / FKS2;
  const float* Arow = A + (size_t)row * NN + ks * KSEG;
  const float* Yb = Y2s + (size_t)batch * NN * CC;
  const int kbase = ks * KSEG;
  float acc[16];
#pragma unroll
  for (int c = 0; c < 16; ++c) acc[c] = 0.f;
  float4 a0 = *(const float4*)(Arow);
  float4 a1 = *(const float4*)(Arow + 4);
  for (int k = 0; k < KSEG; k += 8) {
    const int kn = (k + 8 < KSEG) ? (k + 8) : 0;
    float4 n0 = *(const float4*)(Arow + kn);
    float4 n1 = *(const float4*)(Arow + kn + 4);
    const float av[8] = {a0.x, a0.y, a0.z, a0.w, a1.x, a1.y, a1.z, a1.w};
#pragma unroll
    for (int j = 0; j < 8; ++j) {
      const float* yr = Yb + (size_t)(kbase + k + j) * CC;
#pragma unroll
      for (int c = 0; c < 16; ++c) acc[c] += av[j] * yr[c];
    }
    a0 = n0; a1 = n1;
  }
  float* Zp = Z2 + ((size_t)ks * BN + row) * CC;
#pragma unroll
  for (int c = 0; c < 16; c += 4) {
    float4 v; v.x = acc[c]; v.y = acc[c+1]; v.z = acc[c+2]; v.w = acc[c+3];
    *(float4*)(Zp + c) = v;
  }
}

__global__ __launch_bounds__(256) void d_final(const float* __restrict__ Z2,
    const float* __restrict__ Y2s, const float* __restrict__ dis,
    const float* __restrict__ b2, float* __restrict__ out)
{
  const int gid = blockIdx.x * 256 + threadIdx.x;
  const int r = gid >> 2, q = gid & 3;
  const size_t o = (size_t)r * CC + q * 4;
  float4 s = *(const float4*)(Y2s + o);
#pragma unroll
  for (int p = 0; p < FKS2; ++p) {
    const float4 zp = *(const float4*)(Z2 + (size_t)p * BN * CC + o);
    s.x += zp.x; s.y += zp.y; s.z += zp.z; s.w += zp.w;
  }
  const float dv = dis[r];
  const float4 bb = *(const float4*)(b2 + q * 4);
  float4 res;
  res.x = dv * s.x + bb.x;
  res.y = dv * s.y + bb.y;
  res.z = dv * s.z + bb.z;
  res.w = dv * s.w + bb.w;
  *(float4*)(out + o) = res;
}

extern "C" void kernel_launch(void* const* d_in, const int* in_sizes, int n_in,
                              void* d_out, int out_size, void* d_ws, size_t ws_size,
                              hipStream_t stream) {
  const float* X  = (const float*)d_in[0];
  const float* A  = (const float*)d_in[1];
  const float* W1 = (const float*)d_in[2];
  const float* b1 = (const float*)d_in[3];
  const float* W2 = (const float*)d_in[4];
  const float* b2 = (const float*)d_in[5];
  float* out = (float*)d_out;
  char* wsb = (char*)d_ws;

  // ws layout (bytes): Abf 64MB | Y1s 2MB | Y1sT 2MB | Hbf 2MB |
  // Y2sT 0.5MB | S2d 1MB | dis 64KB  => 75,038,720 total
  const size_t NEED = 75038720;
  if (ws_size >= NEED) {
    unsigned short* Abf  = (unsigned short*)wsb;
    unsigned short* Y1s  = (unsigned short*)(wsb + 67108864);
    unsigned short* Y1sT = (unsigned short*)(wsb + 69206016);
    unsigned short* Hbf  = (unsigned short*)(wsb + 71303168);
    unsigned short* Y2sT = (unsigned short*)(wsb + 73400320);
    float*          S2d  = (float*)(wsb + 73924608);
    float*          dis  = (float*)(wsb + 74973184);

    k_deg   <<<BN / 4, 256, 0, stream>>>(A, X, W1, dis, Abf, Y1s, Y1sT);
    k_gemm1h<<<1024,   256, 0, stream>>>(Abf, Y1sT, Y1s, dis, b1, Hbf);
    k_epi1  <<<1024,   256, 0, stream>>>(Hbf, dis, W2, Y2sT, S2d);
    k_gemm2o<<<1024,   256, 0, stream>>>(Abf, Y2sT, S2d, dis, b2, out);
  } else {
    // fallback: proven fp32 path (R3)
    float* ws  = (float*)d_ws;
    float* dis = ws;
    float* Y1s = ws + 16384;
    float* Z1  = Y1s + (size_t)BN * DD;
    float* Z2  = Z1;
    float* Y2s = Z1 + (size_t)FKS1 * BN * DD;

    d_deg_xw<<<BN / 4,     256, 0, stream>>>(A, X, W1, dis, Y1s);
    d_gemm1 <<<256 * FKS1, 256, 0, stream>>>(A, Y1s, Z1);
    d_epi1  <<<BN / 4,     256, 0, stream>>>(Z1, Y1s, dis, b1, W2, Y2s);
    d_gemm2 <<<64 * FKS2,  256, 0, stream>>>(A, Y2s, Z2);
    d_final <<<256,        256, 0, stream>>>(Z2, Y2s, dis, b2, out);
  }
}